// Round 5
// baseline (165.637 us; speedup 1.0000x reference)
//
#include <hip/hip_runtime.h>

typedef __bf16 bf16x8 __attribute__((ext_vector_type(8)));
typedef float  f32x4  __attribute__((ext_vector_type(4)));

#define D100 100
#define NROWS (4096*64)            // 262144 rows of X
#define NTILES (NROWS/16)          // 16384 16-row tiles
#define NCT 7                      // col tiles: 7*16 = 112 >= 100
#define NKS 4                      // k steps:  4*32 = 128 >= 100 (k=112 = bias row)
#define FRAG_ELEMS (NCT*NKS*64*8)  // 14336 bf16 fragment elements (28672 B)
#define NBLK 1280                  // 5 blocks/CU * 256 CU, persistent
#define WAVES (NBLK*4)             // 5120 waves, 3-4 tiles each

// ---------------------------------------------------------------------------
// Kernel 1: build M = W^T * S in MFMA fragment order (bf16, zero-padded),
// with the bias row folded in at k==112: M[112][n] = (b*S)[n].
// M[k][n] = sum_d W[d*100+k] * S[d*100+n].
// Fragment order: wsM[((ct*4+ks)*64 + lane)*8 + j] holds
//   M[ ks*32 + (lane>>4)*8 + j ][ ct*16 + (lane&15) ]
// ---------------------------------------------------------------------------
__global__ __launch_bounds__(256) void prep_kernel(
    const float* __restrict__ W, const float* __restrict__ bvec,
    const float* __restrict__ S, __bf16* __restrict__ wsM) {
  int tid = blockIdx.x * 256 + threadIdx.x;
  if (tid >= FRAG_ELEMS) return;
  int j    = tid & 7;
  int lane = (tid >> 3) & 63;
  int ks   = (tid >> 9) & 3;
  int ct   = tid >> 11;
  int k = ks * 32 + ((lane >> 4) * 8) + j;
  int n = ct * 16 + (lane & 15);
  float acc = 0.f;
  if (n < D100) {
    if (k < D100) {
      float a0 = 0.f, a1 = 0.f, a2 = 0.f, a3 = 0.f;
      for (int d = 0; d < D100; d += 4) {
        a0 += W[(d + 0) * D100 + k] * S[(d + 0) * D100 + n];
        a1 += W[(d + 1) * D100 + k] * S[(d + 1) * D100 + n];
        a2 += W[(d + 2) * D100 + k] * S[(d + 2) * D100 + n];
        a3 += W[(d + 3) * D100 + k] * S[(d + 3) * D100 + n];
      }
      acc = (a0 + a1) + (a2 + a3);
    } else if (k == 112) {  // bias row
      for (int d = 0; d < D100; ++d) acc += bvec[d] * S[d * D100 + n];
    }
  }
  wsM[tid] = (__bf16)acc;
}

// ---------------------------------------------------------------------------
// Kernel 2: out[r][n] = sum_k x[r][k] * M[k][n]   (bias via M[112], xf=1)
// Persistent: 1280 blocks (5/CU resident), each wave grid-strides 3-4
// 16-row tiles with double-buffered x registers so loads(t+1), MFMAs(t)
// and stores overlap. Swapped operands (M-frag = A, x-frag = B) so lane
// (l16=row, lg) reg q holds out[row][ct*16+lg*4+q] -> direct f32x4 stores.
// Plain (cached) stores: L2 merges the 64B row segments into full lines
// (nontemporal stores caused 3.2x write inflation via partial-line RMW).
// ---------------------------------------------------------------------------
__global__ __launch_bounds__(256, 5) void gemm_kernel(
    const float* __restrict__ x, const __bf16* __restrict__ wsM,
    float* __restrict__ out) {
  __shared__ __align__(16) __bf16 ldsB[FRAG_ELEMS];  // 28672 B

  const int t    = threadIdx.x;
  const int lane = t & 63;
  const int l16  = lane & 15;
  const int lg   = lane >> 4;
  const int gwave = blockIdx.x * 4 + (t >> 6);

  // --- stage M fragments into LDS: 1792 x 16B chunks, 7 per thread ---
  {
    const f32x4* src = (const f32x4*)wsM;
    f32x4*       dst = (f32x4*)ldsB;
#pragma unroll
    for (int i = 0; i < 7; ++i) dst[i * 256 + t] = src[i * 256 + t];
  }

  auto load_tile = [&](int tile, f32x4 (&xv)[7]) {
    const float* xr = x + (size_t)tile * (16 * D100) + l16 * D100;
#pragma unroll
    for (int ks = 0; ks < 3; ++ks) {
      xv[ks * 2]     = *(const f32x4*)(xr + ks * 32 + lg * 8);
      xv[ks * 2 + 1] = *(const f32x4*)(xr + ks * 32 + lg * 8 + 4);
    }
    xv[6] = (lg == 0) ? *(const f32x4*)(xr + 96) : (f32x4){0.f, 0.f, 0.f, 0.f};
  };

  const bf16x8* Bv = (const bf16x8*)ldsB;

  auto compute_store = [&](int tile, const f32x4 (&xv)[7]) {
    f32x4 acc[NCT];
#pragma unroll
    for (int ct = 0; ct < NCT; ++ct) acc[ct] = (f32x4){0.f, 0.f, 0.f, 0.f};

#pragma unroll
    for (int ks = 0; ks < NKS; ++ks) {
      bf16x8 xf;
      if (ks < 3) {
        f32x4 v0 = xv[ks * 2], v1 = xv[ks * 2 + 1];
#pragma unroll
        for (int j = 0; j < 4; ++j) {
          xf[j]     = (__bf16)v0[j];
          xf[j + 4] = (__bf16)v1[j];
        }
      } else {
        // k = 96 + lg*8 + j: lg==0 -> x[96..99]; lg==2,j==0 (k=112) -> 1.0
        f32x4 v0 = xv[6];
#pragma unroll
        for (int j = 0; j < 4; ++j) {
          xf[j]     = (__bf16)v0[j];
          xf[j + 4] = (__bf16)0.f;
        }
        if (lg == 2) xf[0] = (__bf16)1.0f;
      }
#pragma unroll
      for (int ct = 0; ct < NCT; ++ct)
        acc[ct] = __builtin_amdgcn_mfma_f32_16x16x32_bf16(
            Bv[(ct * NKS + ks) * 64 + lane], xf, acc[ct], 0, 0, 0);
    }

    float* orow = out + (size_t)tile * (16 * D100) + l16 * D100 + lg * 4;
#pragma unroll
    for (int ct = 0; ct < NCT; ++ct) {
      if (ct < 6 || lg == 0)  // cols 100..111 don't exist
        *(f32x4*)(orow + ct * 16) = acc[ct];
    }
  };

  // --- software-pipelined grid-stride loop (manual ping-pong, static regs) ---
  f32x4 xva[7], xvb[7];
  int tile = gwave;
  load_tile(tile, xva);
  __syncthreads();  // ldsB ready

  for (;;) {
    int n1 = tile + WAVES;
    if (n1 < NTILES) load_tile(n1, xvb);
    compute_store(tile, xva);
    if (n1 >= NTILES) break;

    tile = n1;
    int n2 = tile + WAVES;
    if (n2 < NTILES) load_tile(n2, xva);
    compute_store(tile, xvb);
    if (n2 >= NTILES) break;
    tile = n2;
  }
}

extern "C" void kernel_launch(void* const* d_in, const int* in_sizes, int n_in,
                              void* d_out, int out_size, void* d_ws,
                              size_t ws_size, hipStream_t stream) {
  const float* x = (const float*)d_in[0];
  const float* W = (const float*)d_in[1];
  const float* b = (const float*)d_in[2];
  const float* S = (const float*)d_in[3];
  __bf16* wsM = (__bf16*)d_ws;
  float*  out = (float*)d_out;

  hipLaunchKernelGGL(prep_kernel, dim3(56), dim3(256), 0, stream,
                     W, b, S, wsM);
  hipLaunchKernelGGL(gemm_kernel, dim3(NBLK), dim3(256), 0, stream,
                     x, wsM, out);
}

// Round 6
// 96.852 us; speedup vs baseline: 1.7102x; 1.7102x over previous
//
#include <hip/hip_runtime.h>

typedef __bf16 bf16x8 __attribute__((ext_vector_type(8)));
typedef float  f32x4  __attribute__((ext_vector_type(4)));

#define D100 100
#define NROWS (4096*64)            // 262144 rows of X
#define NTILES (NROWS/16)          // 16384 16-row tiles
#define NCT 7                      // col tiles: 7*16 = 112 >= 100
#define NKS 4                      // k steps:  4*32 = 128 >= 100 (k=112 = bias row)
#define FRAG_ELEMS (NCT*NKS*64*8)  // 14336 bf16 fragment elements (28672 B)
#define NBLK (NTILES/16)           // 1024 blocks; 4 waves x 4 contiguous tiles

// ---------------------------------------------------------------------------
// Kernel 1: build M = W^T * S in MFMA fragment order (bf16, zero-padded),
// with the bias row folded in at k==112: M[112][n] = (b*S)[n].
// M[k][n] = sum_d W[d*100+k] * S[d*100+n].
// Fragment order: wsM[((ct*4+ks)*64 + lane)*8 + j] holds
//   M[ ks*32 + (lane>>4)*8 + j ][ ct*16 + (lane&15) ]
// ---------------------------------------------------------------------------
__global__ __launch_bounds__(256) void prep_kernel(
    const float* __restrict__ W, const float* __restrict__ bvec,
    const float* __restrict__ S, __bf16* __restrict__ wsM) {
  int tid = blockIdx.x * 256 + threadIdx.x;
  if (tid >= FRAG_ELEMS) return;
  int j    = tid & 7;
  int lane = (tid >> 3) & 63;
  int ks   = (tid >> 9) & 3;
  int ct   = tid >> 11;
  int k = ks * 32 + ((lane >> 4) * 8) + j;
  int n = ct * 16 + (lane & 15);
  float acc = 0.f;
  if (n < D100) {
    if (k < D100) {
      float a0 = 0.f, a1 = 0.f, a2 = 0.f, a3 = 0.f;
      for (int d = 0; d < D100; d += 4) {
        a0 += W[(d + 0) * D100 + k] * S[(d + 0) * D100 + n];
        a1 += W[(d + 1) * D100 + k] * S[(d + 1) * D100 + n];
        a2 += W[(d + 2) * D100 + k] * S[(d + 2) * D100 + n];
        a3 += W[(d + 3) * D100 + k] * S[(d + 3) * D100 + n];
      }
      acc = (a0 + a1) + (a2 + a3);
    } else if (k == 112) {  // bias row
      for (int d = 0; d < D100; ++d) acc += bvec[d] * S[d * D100 + n];
    }
  }
  wsM[tid] = (__bf16)acc;
}

// ---------------------------------------------------------------------------
// Kernel 2: out[r][n] = sum_k x[r][k] * M[k][n]   (bias via M[112], xf=1)
// 1024 blocks x 4 waves; wave w owns 4 CONTIGUOUS tiles base..base+3
// (block writes 102 KB contiguous). Statically-unrolled ping-pong: loads of
// tile t+2 overlap compute of t; each tile's 7 f32x4 stores stay in a tight
// burst right after its MFMAs so L2 merges the 64B halves into full 128B
// lines (grid-stride/dynamic-loop scheduling broke this -> 3x write RMW).
// Swapped operands (M-frag = A, x-frag = B): lane (l16=row, lg) reg q holds
// out[row][ct*16+lg*4+q] -> direct aligned f32x4 stores.
// ---------------------------------------------------------------------------
__global__ __launch_bounds__(256, 5) void gemm_kernel(
    const float* __restrict__ x, const __bf16* __restrict__ wsM,
    float* __restrict__ out) {
  __shared__ __align__(16) __bf16 ldsB[FRAG_ELEMS];  // 28672 B

  const int t    = threadIdx.x;
  const int lane = t & 63;
  const int l16  = lane & 15;
  const int lg   = lane >> 4;
  const int base = blockIdx.x * 16 + (t >> 6) * 4;  // wave's first tile

  // --- stage M fragments into LDS: 1792 x 16B chunks, 7 per thread ---
  {
    const f32x4* src = (const f32x4*)wsM;
    f32x4*       dst = (f32x4*)ldsB;
#pragma unroll
    for (int i = 0; i < 7; ++i) dst[i * 256 + t] = src[i * 256 + t];
  }

  auto load_tile = [&](int tile, f32x4 (&xv)[7]) {
    const float* xr = x + (size_t)tile * (16 * D100) + l16 * D100;
#pragma unroll
    for (int ks = 0; ks < 3; ++ks) {
      xv[ks * 2]     = *(const f32x4*)(xr + ks * 32 + lg * 8);
      xv[ks * 2 + 1] = *(const f32x4*)(xr + ks * 32 + lg * 8 + 4);
    }
    xv[6] = (lg == 0) ? *(const f32x4*)(xr + 96) : (f32x4){0.f, 0.f, 0.f, 0.f};
  };

  const bf16x8* Bv = (const bf16x8*)ldsB;

  auto compute_store = [&](int tile, const f32x4 (&xv)[7]) {
    f32x4 acc[NCT];
#pragma unroll
    for (int ct = 0; ct < NCT; ++ct) acc[ct] = (f32x4){0.f, 0.f, 0.f, 0.f};

#pragma unroll
    for (int ks = 0; ks < NKS; ++ks) {
      bf16x8 xf;
      if (ks < 3) {
        f32x4 v0 = xv[ks * 2], v1 = xv[ks * 2 + 1];
#pragma unroll
        for (int j = 0; j < 4; ++j) {
          xf[j]     = (__bf16)v0[j];
          xf[j + 4] = (__bf16)v1[j];
        }
      } else {
        // k = 96 + lg*8 + j: lg==0 -> x[96..99]; lg==2,j==0 (k=112) -> 1.0
        f32x4 v0 = xv[6];
#pragma unroll
        for (int j = 0; j < 4; ++j) {
          xf[j]     = (__bf16)v0[j];
          xf[j + 4] = (__bf16)0.f;
        }
        if (lg == 2) xf[0] = (__bf16)1.0f;
      }
#pragma unroll
      for (int ct = 0; ct < NCT; ++ct)
        acc[ct] = __builtin_amdgcn_mfma_f32_16x16x32_bf16(
            Bv[(ct * NKS + ks) * 64 + lane], xf, acc[ct], 0, 0, 0);
    }

    float* orow = out + (size_t)tile * (16 * D100) + l16 * D100 + lg * 4;
#pragma unroll
    for (int ct = 0; ct < NCT; ++ct) {
      if (ct < 6 || lg == 0)  // cols 100..111 don't exist
        *(f32x4*)(orow + ct * 16) = acc[ct];
    }
  };

  // --- statically-unrolled 4-tile pipeline (all tile indices constant) ---
  f32x4 xva[7], xvb[7];
  load_tile(base + 0, xva);
  load_tile(base + 1, xvb);
  __syncthreads();  // ldsB ready

  compute_store(base + 0, xva);
  load_tile(base + 2, xva);
  compute_store(base + 1, xvb);
  load_tile(base + 3, xvb);
  compute_store(base + 2, xva);
  compute_store(base + 3, xvb);
}

extern "C" void kernel_launch(void* const* d_in, const int* in_sizes, int n_in,
                              void* d_out, int out_size, void* d_ws,
                              size_t ws_size, hipStream_t stream) {
  const float* x = (const float*)d_in[0];
  const float* W = (const float*)d_in[1];
  const float* b = (const float*)d_in[2];
  const float* S = (const float*)d_in[3];
  __bf16* wsM = (__bf16*)d_ws;
  float*  out = (float*)d_out;

  hipLaunchKernelGGL(prep_kernel, dim3(56), dim3(256), 0, stream,
                     W, b, S, wsM);
  hipLaunchKernelGGL(gemm_kernel, dim3(NBLK), dim3(256), 0, stream,
                     x, wsM, out);
}

// Round 7
// 49.853 us; speedup vs baseline: 3.3225x; 1.9427x over previous
//
#include <hip/hip_runtime.h>

typedef __bf16 bf16x8 __attribute__((ext_vector_type(8)));
typedef float  f32x4  __attribute__((ext_vector_type(4)));

#define D100 100
#define NROWS (4096*64)            // 262144 rows of X
#define NTILES (NROWS/16)          // 16384 16-row tiles
#define NCT 7                      // col tiles: 7*16 = 112 >= 100
#define NKS 4                      // k steps:  4*32 = 128 >= 100 (k=112 = bias row)
#define FRAG_ELEMS (NCT*NKS*64*8)  // 14336 bf16 fragment elements (28672 B)
#define NBLK (NTILES/8)            // 2048 blocks; 8 waves, ONE tile per wave

// ---------------------------------------------------------------------------
// Kernel 1: build M = W^T * S in MFMA fragment order (bf16, zero-padded),
// with the bias row folded in at k==112: M[112][n] = (b*S)[n].
// M[k][n] = sum_d W[d*100+k] * S[d*100+n].
// Fragment order: wsM[((ct*4+ks)*64 + lane)*8 + j] holds
//   M[ ks*32 + (lane>>4)*8 + j ][ ct*16 + (lane&15) ]
// ---------------------------------------------------------------------------
__global__ __launch_bounds__(256) void prep_kernel(
    const float* __restrict__ W, const float* __restrict__ bvec,
    const float* __restrict__ S, __bf16* __restrict__ wsM) {
  int tid = blockIdx.x * 256 + threadIdx.x;
  if (tid >= FRAG_ELEMS) return;
  int j    = tid & 7;
  int lane = (tid >> 3) & 63;
  int ks   = (tid >> 9) & 3;
  int ct   = tid >> 11;
  int k = ks * 32 + ((lane >> 4) * 8) + j;
  int n = ct * 16 + (lane & 15);
  float acc = 0.f;
  if (n < D100) {
    if (k < D100) {
      float a0 = 0.f, a1 = 0.f, a2 = 0.f, a3 = 0.f;
      for (int d = 0; d < D100; d += 4) {
        a0 += W[(d + 0) * D100 + k] * S[(d + 0) * D100 + n];
        a1 += W[(d + 1) * D100 + k] * S[(d + 1) * D100 + n];
        a2 += W[(d + 2) * D100 + k] * S[(d + 2) * D100 + n];
        a3 += W[(d + 3) * D100 + k] * S[(d + 3) * D100 + n];
      }
      acc = (a0 + a1) + (a2 + a3);
    } else if (k == 112) {  // bias row
      for (int d = 0; d < D100; ++d) acc += bvec[d] * S[d * D100 + n];
    }
  }
  wsM[tid] = (__bf16)acc;
}

// ---------------------------------------------------------------------------
// Kernel 2: out[r][n] = sum_k x[r][k] * M[k][n]   (bias via M[112], xf=1)
// 2048 blocks x 8 waves (512 thr); wave w computes ONE 16-row tile
// (blockIdx*8 + w), does a tight 7-store f32x4 burst, and exits.
// EMPIRICAL INVARIANT (r3 vs r4/r5/r6): a wave that issues streaming loads
// after its store burst inflates HBM writes 1.6-2.9x (partial-line dirty
// evictions -> RMW). One-tile-per-wave + exit keeps WRITE_SIZE == output.
// Swapped operands (M-frag = A, x-frag = B): lane (l16=row, lg) reg q holds
// out[row][ct*16+lg*4+q] -> direct aligned f32x4 stores.
// ---------------------------------------------------------------------------
__global__ __launch_bounds__(512, 8) void gemm_kernel(
    const float* __restrict__ x, const __bf16* __restrict__ wsM,
    float* __restrict__ out) {
  __shared__ __align__(16) __bf16 ldsB[FRAG_ELEMS];  // 28672 B

  const int t    = threadIdx.x;
  const int lane = t & 63;
  const int l16  = lane & 15;
  const int lg   = lane >> 4;
  const int tile = blockIdx.x * 8 + (t >> 6);

  // --- issue the long-latency x loads FIRST (7 x f32x4 per lane) ---
  const float* xr = x + (size_t)tile * (16 * D100) + l16 * D100;
  f32x4 xv[7];
#pragma unroll
  for (int ks = 0; ks < 3; ++ks) {
    xv[ks * 2]     = *(const f32x4*)(xr + ks * 32 + lg * 8);
    xv[ks * 2 + 1] = *(const f32x4*)(xr + ks * 32 + lg * 8 + 4);
  }
  xv[6] = (lg == 0) ? *(const f32x4*)(xr + 96) : (f32x4){0.f, 0.f, 0.f, 0.f};

  // --- stage M fragments into LDS: 1792 x 16B chunks (L2-hot) ---
  {
    const f32x4* src = (const f32x4*)wsM;
    f32x4*       dst = (f32x4*)ldsB;
    dst[t]        = src[t];
    dst[512 + t]  = src[512 + t];
    dst[1024 + t] = src[1024 + t];
    if (t < 256) dst[1536 + t] = src[1536 + t];
  }
  __syncthreads();  // ldsB ready

  f32x4 acc[NCT];
#pragma unroll
  for (int ct = 0; ct < NCT; ++ct) acc[ct] = (f32x4){0.f, 0.f, 0.f, 0.f};

  const bf16x8* Bv = (const bf16x8*)ldsB;
#pragma unroll
  for (int ks = 0; ks < NKS; ++ks) {
    bf16x8 xf;
    if (ks < 3) {
      f32x4 v0 = xv[ks * 2], v1 = xv[ks * 2 + 1];
#pragma unroll
      for (int j = 0; j < 4; ++j) {
        xf[j]     = (__bf16)v0[j];
        xf[j + 4] = (__bf16)v1[j];
      }
    } else {
      // k = 96 + lg*8 + j: lg==0 -> x[96..99]; lg==2,j==0 (k=112) -> 1.0
      f32x4 v0 = xv[6];
#pragma unroll
      for (int j = 0; j < 4; ++j) {
        xf[j]     = (__bf16)v0[j];
        xf[j + 4] = (__bf16)0.f;
      }
      if (lg == 2) xf[0] = (__bf16)1.0f;
    }
#pragma unroll
    for (int ct = 0; ct < NCT; ++ct)
      acc[ct] = __builtin_amdgcn_mfma_f32_16x16x32_bf16(
          Bv[(ct * NKS + ks) * 64 + lane], xf, acc[ct], 0, 0, 0);
  }

  // --- tight store burst, then the wave exits ---
  float* orow = out + (size_t)tile * (16 * D100) + l16 * D100 + lg * 4;
#pragma unroll
  for (int ct = 0; ct < NCT; ++ct) {
    if (ct < 6 || lg == 0)  // cols 100..111 don't exist
      *(f32x4*)(orow + ct * 16) = acc[ct];
  }
}

extern "C" void kernel_launch(void* const* d_in, const int* in_sizes, int n_in,
                              void* d_out, int out_size, void* d_ws,
                              size_t ws_size, hipStream_t stream) {
  const float* x = (const float*)d_in[0];
  const float* W = (const float*)d_in[1];
  const float* b = (const float*)d_in[2];
  const float* S = (const float*)d_in[3];
  __bf16* wsM = (__bf16*)d_ws;
  float*  out = (float*)d_out;

  hipLaunchKernelGGL(prep_kernel, dim3(56), dim3(256), 0, stream,
                     W, b, S, wsM);
  hipLaunchKernelGGL(gemm_kernel, dim3(NBLK), dim3(512), 0, stream,
                     x, wsM, out);
}

// Round 8
// 45.177 us; speedup vs baseline: 3.6664x; 1.1035x over previous
//
#include <hip/hip_runtime.h>

typedef __bf16 bf16x8 __attribute__((ext_vector_type(8)));
typedef float  f32x4  __attribute__((ext_vector_type(4)));

#define D100 100
#define NROWS (4096*64)            // 262144 rows of X
#define NTILES (NROWS/16)          // 16384 16-row tiles
#define NCT 7                      // col tiles: 7*16 = 112 >= 100
#define NKS 4                      // k steps: 4*32 = 128 (k=112 = bias row)
#define FRAG_ELEMS (NCT*NKS*64*8)  // 14336 bf16 fragment elements (28672 B)
#define TILE_B 6400                // bytes per 16x100 f32 tile
#define NBLK (NTILES/8)            // 2048 blocks; 8 waves, ONE tile per wave

typedef const __attribute__((address_space(1))) void gvoid;
typedef __attribute__((address_space(3))) void lvoid;

// ---------------------------------------------------------------------------
// Kernel 1: build M = W^T * S in MFMA fragment order (bf16, zero-padded),
// with the bias row folded in at k==112: M[112][n] = (b*S)[n].
// M[k][n] = sum_d W[d*100+k] * S[d*100+n].
// Fragment order: wsM[((ct*4+ks)*64 + lane)*8 + j] holds
//   M[ ks*32 + (lane>>4)*8 + j ][ ct*16 + (lane&15) ]
// ---------------------------------------------------------------------------
__global__ __launch_bounds__(256) void prep_kernel(
    const float* __restrict__ W, const float* __restrict__ bvec,
    const float* __restrict__ S, __bf16* __restrict__ wsM) {
  int tid = blockIdx.x * 256 + threadIdx.x;
  if (tid >= FRAG_ELEMS) return;
  int j    = tid & 7;
  int lane = (tid >> 3) & 63;
  int ks   = (tid >> 9) & 3;
  int ct   = tid >> 11;
  int k = ks * 32 + ((lane >> 4) * 8) + j;
  int n = ct * 16 + (lane & 15);
  float acc = 0.f;
  if (n < D100) {
    if (k < D100) {
      float a0 = 0.f, a1 = 0.f, a2 = 0.f, a3 = 0.f;
      for (int d = 0; d < D100; d += 4) {
        a0 += W[(d + 0) * D100 + k] * S[(d + 0) * D100 + n];
        a1 += W[(d + 1) * D100 + k] * S[(d + 1) * D100 + n];
        a2 += W[(d + 2) * D100 + k] * S[(d + 2) * D100 + n];
        a3 += W[(d + 3) * D100 + k] * S[(d + 3) * D100 + n];
      }
      acc = (a0 + a1) + (a2 + a3);
    } else if (k == 112) {  // bias row
      for (int d = 0; d < D100; ++d) acc += bvec[d] * S[d * D100 + n];
    }
  }
  wsM[tid] = (__bf16)acc;
}

// ---------------------------------------------------------------------------
// Kernel 2: out[r][n] = sum_k x[r][k] * M[k][n]   (bias via M[112], xf=1)
// TRANSACTION-MINIMAL version. Evidence (r3 vs r7 vs fillBuffer): the memory
// system caps at ~56-63 G transactions/s; scattered 16B-per-lane fragment
// accesses (~224 trans/tile) were the limiter, not bytes. Here every global
// access is linear 16B/lane -> 1KB contiguous per wave-instruction (full
// 128B lines): x -> LDS via global_load_lds; MFMA fragments via ds_read;
// acc scattered back into the wave-private LDS region; linear copy-out.
// Stores remain a terminal burst; wave exits (clean-merge invariant).
// ---------------------------------------------------------------------------
__global__ __launch_bounds__(512, 4) void gemm_kernel(
    const float* __restrict__ x, const __bf16* __restrict__ wsM,
    float* __restrict__ out) {
  __shared__ __align__(16) __bf16 ldsB[FRAG_ELEMS];   // 28672 B
  __shared__ __align__(16) float  ldsX[8 * 1600];     // 51200 B (6400 B/wave)

  const int t    = threadIdx.x;
  const int lane = t & 63;
  const int l16  = lane & 15;
  const int lg   = lane >> 4;
  const int w    = t >> 6;
  const int tile = blockIdx.x * 8 + w;

  // ---- x tile -> LDS, linear (1KB per instruction, full lines) ----
  const char* xsrc = (const char*)x + (size_t)tile * TILE_B + (size_t)lane * 16;
  char* ldsx = (char*)(ldsX + w * 1600);  // wave-private 6400 B
#pragma unroll
  for (int c = 0; c < 6; ++c)
    __builtin_amdgcn_global_load_lds((gvoid*)(xsrc + c * 1024),
                                     (lvoid*)(ldsx + c * 1024), 16, 0, 0);
  if (lane < 16)  // tail: bytes 6144..6400 (2 full lines)
    __builtin_amdgcn_global_load_lds((gvoid*)(xsrc + 6144),
                                     (lvoid*)(ldsx + 6144), 16, 0, 0);

  // ---- M fragments -> LDS, linear (28 x 1KB chunks split across waves) ----
  {
    const char* bsrc = (const char*)wsM + (size_t)lane * 16;
    for (int c = w; c < 28; c += 8)
      __builtin_amdgcn_global_load_lds((gvoid*)(bsrc + c * 1024),
                                       (lvoid*)((char*)ldsB + c * 1024),
                                       16, 0, 0);
  }
  __syncthreads();  // drains vmcnt (all global_load_lds) + syncs ldsB

  f32x4 acc[NCT];
#pragma unroll
  for (int ct = 0; ct < NCT; ++ct) acc[ct] = (f32x4){0.f, 0.f, 0.f, 0.f};

  const bf16x8* Bv = (const bf16x8*)ldsB;
  const char* xrow = ldsx + l16 * 400;

#pragma unroll
  for (int ks = 0; ks < NKS; ++ks) {
    bf16x8 xf;
    if (ks < 3) {
      f32x4 v0 = *(const f32x4*)(xrow + ks * 128 + lg * 32);
      f32x4 v1 = *(const f32x4*)(xrow + ks * 128 + lg * 32 + 16);
#pragma unroll
      for (int j = 0; j < 4; ++j) {
        xf[j]     = (__bf16)v0[j];
        xf[j + 4] = (__bf16)v1[j];
      }
    } else {
      // k = 96 + lg*8 + j: lg==0 -> x[96..99]; lg==2,j==0 (k=112) -> 1.0
      f32x4 v0 = (lg == 0) ? *(const f32x4*)(xrow + 384)
                           : (f32x4){0.f, 0.f, 0.f, 0.f};
#pragma unroll
      for (int j = 0; j < 4; ++j) {
        xf[j]     = (__bf16)v0[j];
        xf[j + 4] = (__bf16)0.f;
      }
      if (lg == 2) xf[0] = (__bf16)1.0f;
    }
#pragma unroll
    for (int ct = 0; ct < NCT; ++ct)
      acc[ct] = __builtin_amdgcn_mfma_f32_16x16x32_bf16(
          Bv[(ct * NKS + ks) * 64 + lane], xf, acc[ct], 0, 0, 0);
  }

  // ---- scatter acc into the (consumed) wave-private x region ----
  // acc[ct][q] = out[row=l16][col=ct*16+lg*4+q] -> byte l16*400+ct*64+lg*16
#pragma unroll
  for (int ct = 0; ct < NCT; ++ct) {
    if (ct < 6 || lg == 0)  // cols 100..111 don't exist
      *(f32x4*)(ldsx + l16 * 400 + ct * 64 + lg * 16) = acc[ct];
  }

  // ---- terminal linear store burst (1KB/instr, full lines), then exit ----
  char* dst = (char*)(out + (size_t)tile * 1600) + (size_t)lane * 16;
#pragma unroll
  for (int c = 0; c < 6; ++c) {
    f32x4 v = *(const f32x4*)(ldsx + c * 1024 + lane * 16);
    *(f32x4*)(dst + c * 1024) = v;
  }
  if (lane < 16) {
    f32x4 v = *(const f32x4*)(ldsx + 6144 + lane * 16);
    *(f32x4*)(dst + 6144) = v;
  }
}

extern "C" void kernel_launch(void* const* d_in, const int* in_sizes, int n_in,
                              void* d_out, int out_size, void* d_ws,
                              size_t ws_size, hipStream_t stream) {
  const float* x = (const float*)d_in[0];
  const float* W = (const float*)d_in[1];
  const float* b = (const float*)d_in[2];
  const float* S = (const float*)d_in[3];
  __bf16* wsM = (__bf16*)d_ws;
  float*  out = (float*)d_out;

  hipLaunchKernelGGL(prep_kernel, dim3(56), dim3(256), 0, stream,
                     W, b, S, wsM);
  hipLaunchKernelGGL(gemm_kernel, dim3(NBLK), dim3(512), 0, stream,
                     x, wsM, out);
}